// Round 9
// baseline (1283.286 us; speedup 1.0000x reference)
//
#include <hip/hip_runtime.h>
#include <hip/hip_bf16.h>
#include <stdint.h>

#define E_N 16
#define TOPK 4
#define DD 2560
#define FF 1664
#define FSS 3328
#define TT 2048

typedef __attribute__((ext_vector_type(8))) __bf16 bf16x8;
typedef __attribute__((ext_vector_type(4))) float f32x4;

__device__ __forceinline__ unsigned short f2bf(float f) {
  return __builtin_bit_cast(unsigned short, (__bf16)f);
}
__device__ __forceinline__ float bf2f(unsigned short u) {
  return __builtin_bit_cast(float, (unsigned int)u << 16);
}
__device__ __forceinline__ unsigned int pk2(float a, float b) {
  return (unsigned int)f2bf(a) | ((unsigned int)f2bf(b) << 16);
}

#define GLOAD16(g, l)                                                          \
  __builtin_amdgcn_global_load_lds(                                            \
      (const __attribute__((address_space(1))) void*)(g),                      \
      (__attribute__((address_space(3))) void*)(l), 16, 0, 0)

#define SBAR() __builtin_amdgcn_s_barrier()
#define SCHED0() __builtin_amdgcn_sched_barrier(0)
#define VMW(N) asm volatile("s_waitcnt vmcnt(" #N ")" ::: "memory")

// swizzled block decompose: XCD-chunked bijective remap (requires nwg%8==0)
__device__ __forceinline__ void swz_block(int& bm, int& bn, int& bz) {
  int gx = gridDim.x, gy = gridDim.y;
  int nwg = gx * gy * gridDim.z;
  int flat = blockIdx.x + gx * (blockIdx.y + gy * blockIdx.z);
  if ((nwg & 7) == 0) flat = (flat & 7) * (nwg >> 3) + (flat >> 3);
  bm = flat % gx;
  int rest = flat / gx;
  bn = rest % gy;
  bz = rest / gy;
}

// ---------------- X -> bf16 ----------------
__global__ __launch_bounds__(256) void cvt_bf16_kernel(const float* __restrict__ in,
                                                       unsigned short* __restrict__ out) {
  size_t i = ((size_t)blockIdx.x * 256 + threadIdx.x) * 4;
  float4 v = *reinterpret_cast<const float4*>(in + i);
  ushort4 o;
  o.x = f2bf(v.x); o.y = f2bf(v.y); o.z = f2bf(v.z); o.w = f2bf(v.w);
  *reinterpret_cast<ushort4*>(out + i) = o;
}

// ---------------- weight transpose+convert: [K][N] f32 -> [N][K] bf16 ----------------
__global__ __launch_bounds__(256) void tcvt_kernel(const float* __restrict__ in,
                                                   unsigned short* __restrict__ out,
                                                   int K, int N) {
  __shared__ float lds[64 * 65];
  int z = blockIdx.z;
  in += (size_t)z * K * N;
  out += (size_t)z * K * N;
  int k0 = blockIdx.x * 64, n0 = blockIdx.y * 64;
  int t = threadIdx.x;
#pragma unroll
  for (int j = 0; j < 4; ++j) {
    int idx = j * 256 + t;
    int r = idx >> 4, c = (idx & 15) * 4;
    float4 v = *reinterpret_cast<const float4*>(in + (size_t)(k0 + r) * N + n0 + c);
    lds[r * 65 + c] = v.x;
    lds[r * 65 + c + 1] = v.y;
    lds[r * 65 + c + 2] = v.z;
    lds[r * 65 + c + 3] = v.w;
  }
  __syncthreads();
#pragma unroll
  for (int j = 0; j < 2; ++j) {
    int idx = j * 256 + t;
    int n = idx >> 3, kg = (idx & 7) * 8;
    float a0 = lds[(kg + 0) * 65 + n], a1 = lds[(kg + 1) * 65 + n];
    float a2 = lds[(kg + 2) * 65 + n], a3 = lds[(kg + 3) * 65 + n];
    float a4 = lds[(kg + 4) * 65 + n], a5 = lds[(kg + 5) * 65 + n];
    float a6 = lds[(kg + 6) * 65 + n], a7 = lds[(kg + 7) * 65 + n];
    uint4 o{pk2(a0, a1), pk2(a2, a3), pk2(a4, a5), pk2(a6, a7)};
    *reinterpret_cast<uint4*>(out + (size_t)(n0 + n) * K + k0 + kg) = o;
  }
}

// ---------------- Router ----------------
__global__ __launch_bounds__(256) void router_kernel(const float* __restrict__ x,
                                                     const float* __restrict__ rw,
                                                     int* __restrict__ cnt,
                                                     int* __restrict__ list,
                                                     float* __restrict__ tw) {
  int t = blockIdx.x;
  const float* xr = x + (size_t)t * DD;
  __shared__ float logits[E_N];
  int lane = threadIdx.x & 63, wid = threadIdx.x >> 6;
  for (int ee = 0; ee < 4; ++ee) {
    int e = wid * 4 + ee;
    const float* wr = rw + (size_t)e * DD;
    float p = 0.f;
    for (int d = lane; d < DD; d += 64) p += xr[d] * wr[d];
#pragma unroll
    for (int off = 32; off > 0; off >>= 1) p += __shfl_down(p, off);
    if (lane == 0) logits[e] = p;
  }
  __syncthreads();
  if (threadIdx.x == 0) {
    float mx = -1e30f;
    for (int e = 0; e < E_N; ++e) mx = fmaxf(mx, logits[e]);
    float pe[E_N];
    for (int e = 0; e < E_N; ++e) pe[e] = __expf(logits[e] - mx);
    int idx[TOPK]; float val[TOPK]; float s4 = 0.f;
    unsigned used = 0;
    for (int k = 0; k < TOPK; ++k) {
      int bi = 0; float bv = -1.f;
      for (int e = 0; e < E_N; ++e)
        if (!((used >> e) & 1) && pe[e] > bv) { bv = pe[e]; bi = e; }
      used |= 1u << bi; idx[k] = bi; val[k] = bv; s4 += bv;
    }
    float inv = 1.f / s4;
    for (int k = 0; k < TOPK; ++k) {
      int e2 = idx[k];
      int pos = atomicAdd(&cnt[e2], 1);
      list[e2 * TT + pos] = t * 4 + k;
      tw[t * 4 + k] = val[k] * inv;
    }
  }
}

// ---------------- 8-phase 256x256 GEMM body (m201-style, k-slot staggered) ----------
// BM=BN=256, BK=64, 512 threads / 8 waves (2M x 4N), per-wave 128x64 output.
// LDS: 2 bufs x {A_k0,A_k1,B_k0,B_k1} subtiles (256 rows x 32 bf16, 64B rows).
// Per K-tile: 4 stages (2 gload_lds each), issued 1/phase for tile kt+1.
// vmcnt(4) at ph1 (guards own k1 subtiles) and ph3 (guards next tile's k0).
template <int MODE, int SHIFT>
__device__ __forceinline__ void gemm8(
    const unsigned short* __restrict__ A0, const unsigned short* __restrict__ W0,
    void* __restrict__ O0, const int* lst, const float* __restrict__ tw,
    int M, int Kt, int Nt, int m0, int n0) {
  __shared__ __align__(16) unsigned short lds[2][32768];

  int tid = threadIdx.x, lane = tid & 63, w = tid >> 6;
  int wm = w >> 2, wn = w & 3;

  // staging: thread covers chunk cid = j*512+tid of a 256x32 subtile
  const unsigned short* pA[2];
  const unsigned short* pB[2];
  int ldso[2];
#pragma unroll
  for (int j = 0; j < 2; ++j) {
    int cid = j * 512 + tid;
    int row = cid >> 2, c = cid & 3;
    int cs = c ^ ((row >> 1) & 3);                 // 64B-row swizzle (source side)
    int ar = min(m0 + row, M - 1);
    int code = lst ? lst[ar] : ar;
    int arow = SHIFT ? (lst ? (code >> 2) : code) : code;
    pA[j] = A0 + (size_t)arow * Kt + cs * 8;
    int br = min(n0 + row, Nt - 1);
    pB[j] = W0 + (size_t)br * Kt + cs * 8;
    ldso[j] = cid * 8;
  }

  // stage s: 0=A_k0 1=B_k0 2=A_k1 3=B_k1 of tile kt into buf
  auto stage = [&](int kt, int s, int buf) {
    int koff = kt * 64 + (s >> 1) * 32;
    unsigned short* dst = &lds[buf][(s >> 1) * 8192 + ((s & 1) ? 16384 : 0)];
    if (s & 1) {
      GLOAD16(pB[0] + koff, dst + ldso[0]);
      GLOAD16(pB[1] + koff, dst + ldso[1]);
    } else {
      GLOAD16(pA[0] + koff, dst + ldso[0]);
      GLOAD16(pA[1] + koff, dst + ldso[1]);
    }
  };

  // frag read offsets within a k-slot subtile (64B rows, matching swizzle)
  int cg = lane >> 4;
  int aoff[8], boff[4];
#pragma unroll
  for (int mf = 0; mf < 8; ++mf) {
    int r = wm * 128 + mf * 16 + (lane & 15);
    aoff[mf] = r * 32 + ((cg ^ ((r >> 1) & 3)) * 8);
  }
#pragma unroll
  for (int nf = 0; nf < 4; ++nf) {
    int rb = wn * 64 + nf * 16 + (lane & 15);
    boff[nf] = 16384 + rb * 32 + ((cg ^ ((rb >> 1) & 3)) * 8);
  }

  f32x4 acc[8][4] = {};
  bf16x8 bfr[4];

  int nk = Kt / 64;
  // prologue: all 4 stages of tile 0 into buf0; ensure k0 subtiles landed
  stage(0, 0, 0); stage(0, 1, 0); stage(0, 2, 0); stage(0, 3, 0);
  VMW(4); SCHED0();
  SBAR(); SCHED0();

  for (int kt = 0; kt < nk; ++kt) {
    int buf = kt & 1;
    const unsigned short* L = &lds[buf][0];
    bool pf = (kt + 1 < nk);
#pragma unroll
    for (int ph = 0; ph < 4; ++ph) {
      int ks = ph >> 1;          // k-slot 0,0,1,1
      int mh = ph & 1;           // m-half 0,1
      bf16x8 afr[4];
      if (mh == 0) {
#pragma unroll
        for (int nf = 0; nf < 4; ++nf)
          bfr[nf] = __builtin_bit_cast(bf16x8,
              *reinterpret_cast<const uint4*>(L + ks * 8192 + boff[nf]));
      }
#pragma unroll
      for (int i = 0; i < 4; ++i)
        afr[i] = __builtin_bit_cast(bf16x8,
            *reinterpret_cast<const uint4*>(L + ks * 8192 + aoff[mh * 4 + i]));
      if (pf) stage(kt + 1, ph, buf ^ 1);
      if (ph == 1) {
        if (pf) { VMW(4); } else { VMW(0); }
      } else if (ph == 3 && pf) {
        VMW(4);
      }
      SCHED0();
      SBAR(); SCHED0();
      __builtin_amdgcn_s_setprio(1);
#pragma unroll
      for (int i = 0; i < 4; ++i)
#pragma unroll
        for (int nf = 0; nf < 4; ++nf)
          acc[mh * 4 + i][nf] =
              __builtin_amdgcn_mfma_f32_16x16x32_bf16(afr[i], bfr[nf], acc[mh * 4 + i][nf], 0, 0, 0);
      __builtin_amdgcn_s_setprio(0);
      SCHED0();
      SBAR(); SCHED0();
    }
  }

  // epilogue (C/D: col=lane&15, row=(lane>>4)*4+q per 16x16 frag)
#pragma unroll
  for (int mf = 0; mf < 8; ++mf) {
#pragma unroll
    for (int q = 0; q < 4; ++q) {
      int lr = wm * 128 + mf * 16 + (lane >> 4) * 4 + q;
      int grow = m0 + lr;
      if (grow < M) {
        int code = lst ? lst[grow] : grow;
        int col = n0 + wn * 64 + (lane & 15);
        if (MODE == 0) {
          unsigned short* Op = (unsigned short*)O0 + (size_t)code * Nt + col;
#pragma unroll
          for (int nf = 0; nf < 4; ++nf)
            if (col + nf * 16 < Nt) Op[nf * 16] = f2bf(acc[mf][nf][q]);
        } else {
          float scale = tw ? tw[code] : 1.f;
          float* Op = (float*)O0 + (size_t)code * Nt + col;
#pragma unroll
          for (int nf = 0; nf < 4; ++nf)
            if (col + nf * 16 < Nt) Op[nf * 16] = acc[mf][nf][q] * scale;
        }
      }
    }
  }
}

// ---------------- mega gate+up launch: z=0..15 expert-G, 16 shared-G,
//                  17..32 expert-U, 33 shared-U ----------------
__global__ __launch_bounds__(512, 2) void gu8_kernel(
    const unsigned short* __restrict__ Xb,
    const unsigned short* __restrict__ WgT, const unsigned short* __restrict__ WuT,
    const unsigned short* __restrict__ SgT, const unsigned short* __restrict__ SuT,
    unsigned short* __restrict__ Gx, unsigned short* __restrict__ Ux,
    unsigned short* __restrict__ Gs, unsigned short* __restrict__ Us,
    const int* __restrict__ list, const int* __restrict__ cnt) {
  int bm, bn, z;
  swz_block(bm, bn, z);
  bool up = z >= 17;
  int ze = up ? z - 17 : z;
  const unsigned short* W0;
  unsigned short* O0;
  const int* lst = nullptr;
  int M, Nt;
  if (ze < E_N) {
    M = cnt[ze];
    lst = list + ze * TT;
    Nt = FF;
    W0 = (up ? WuT : WgT) + (size_t)ze * DD * FF;
    O0 = up ? Ux : Gx;
  } else {
    M = TT;
    Nt = FSS;
    W0 = up ? SuT : SgT;
    O0 = up ? Us : Gs;
  }
  int m0 = bm * 256, n0 = bn * 256;
  if (m0 >= M || n0 >= Nt) return;
  gemm8<0, 1>(Xb, W0, O0, lst, nullptr, M, DD, Nt, m0, n0);
}

// ---------------- mega down launch: z=0..15 expert, 16 shared ----------------
__global__ __launch_bounds__(512, 2) void dn8_kernel(
    const unsigned short* __restrict__ Hx, const unsigned short* __restrict__ Hs,
    const unsigned short* __restrict__ WdT, const unsigned short* __restrict__ SdT,
    float* __restrict__ Y, float* __restrict__ Ys,
    const int* __restrict__ list, const int* __restrict__ cnt,
    const float* __restrict__ tw) {
  int bm, bn, z;
  swz_block(bm, bn, z);
  const unsigned short* A0;
  const unsigned short* W0;
  float* O0;
  const int* lst = nullptr;
  const float* sc = nullptr;
  int M, Kt;
  if (z < E_N) {
    M = cnt[z];
    lst = list + z * TT;
    Kt = FF;
    A0 = Hx;
    W0 = WdT + (size_t)z * FF * DD;
    O0 = Y;
    sc = tw;
  } else {
    M = TT;
    Kt = FSS;
    A0 = Hs;
    W0 = SdT;
    O0 = Ys;
  }
  int m0 = bm * 256, n0 = bn * 256;
  if (m0 >= M) return;
  gemm8<1, 0>(A0, W0, O0, lst, sc, M, Kt, DD, m0, n0);
}

// ---------------- h = silu(g) * u, elementwise in-place on u ----------------
__global__ __launch_bounds__(256) void h_kernel(const unsigned short* __restrict__ g,
                                                unsigned short* __restrict__ u) {
  size_t i = ((size_t)blockIdx.x * 256 + threadIdx.x) * 8;
  uint4 gv = *reinterpret_cast<const uint4*>(g + i);
  uint4 uv = *reinterpret_cast<const uint4*>(u + i);
  const unsigned int* gw = reinterpret_cast<const unsigned int*>(&gv);
  const unsigned int* uw = reinterpret_cast<const unsigned int*>(&uv);
  uint4 ov;
  unsigned int* ow = reinterpret_cast<unsigned int*>(&ov);
#pragma unroll
  for (int j = 0; j < 4; ++j) {
    float g0 = bf2f((unsigned short)(gw[j] & 0xffff));
    float g1 = bf2f((unsigned short)(gw[j] >> 16));
    float u0 = bf2f((unsigned short)(uw[j] & 0xffff));
    float u1 = bf2f((unsigned short)(uw[j] >> 16));
    float h0 = (g0 / (1.f + __expf(-g0))) * u0;
    float h1 = (g1 / (1.f + __expf(-g1))) * u1;
    ow[j] = pk2(h0, h1);
  }
  *reinterpret_cast<uint4*>(u + i) = ov;
}

// ---------------- combine ----------------
__global__ __launch_bounds__(256) void combine_kernel(const float* __restrict__ Y,
                                                      const float* __restrict__ Ys,
                                                      float* __restrict__ out) {
  size_t i = ((size_t)blockIdx.x * 256 + threadIdx.x) * 4;
  size_t t = i / DD;
  int d = (int)(i % DD);
  float4 a = *reinterpret_cast<const float4*>(Ys + i);
#pragma unroll
  for (int k = 0; k < 4; ++k) {
    float4 v = *reinterpret_cast<const float4*>(Y + (t * 4 + k) * (size_t)DD + d);
    a.x += v.x; a.y += v.y; a.z += v.z; a.w += v.w;
  }
  *reinterpret_cast<float4*>(out + i) = a;
}

extern "C" void kernel_launch(void* const* d_in, const int* in_sizes, int n_in,
                              void* d_out, int out_size, void* d_ws, size_t ws_size,
                              hipStream_t stream) {
  const float* x  = (const float*)d_in[0];
  const float* rw = (const float*)d_in[1];
  const float* wg = (const float*)d_in[2];
  const float* wu = (const float*)d_in[3];
  const float* wd = (const float*)d_in[4];
  const float* sg = (const float*)d_in[5];
  const float* su = (const float*)d_in[6];
  const float* sd = (const float*)d_in[7];
  float* out = (float*)d_out;

  char* ws = (char*)d_ws;
  size_t off = 0;
  auto alloc = [&](size_t bytes) {
    off = (off + 255) & ~(size_t)255;
    void* p = ws + off;
    off += bytes;
    return p;
  };
  unsigned short* W1 = (unsigned short*)alloc((size_t)E_N * FF * DD * 2);   // 136 MB
  unsigned short* W2 = (unsigned short*)alloc((size_t)E_N * FF * DD * 2);   // 136 MB
  unsigned short* W3 = (unsigned short*)alloc((size_t)FSS * DD * 2);        // 17 MB
  unsigned short* W4 = (unsigned short*)alloc((size_t)FSS * DD * 2);        // 17 MB
  unsigned short* Xb = (unsigned short*)alloc((size_t)TT * DD * 2);
  unsigned short* Gx = (unsigned short*)alloc((size_t)4 * TT * FF * 2);     // raw expert G
  unsigned short* Hx = (unsigned short*)alloc((size_t)4 * TT * FF * 2);     // raw U -> H
  unsigned short* Gs = (unsigned short*)alloc((size_t)TT * FSS * 2);
  unsigned short* Hs = (unsigned short*)alloc((size_t)TT * FSS * 2);
  float* Y  = (float*)alloc((size_t)4 * TT * DD * 4);
  float* Ys = (float*)alloc((size_t)TT * DD * 4);
  float* tw = (float*)alloc((size_t)4 * TT * 4);
  int* cnt  = (int*)alloc(E_N * 4);
  int* list = (int*)alloc((size_t)E_N * TT * 4);
  (void)ws_size; (void)in_sizes; (void)n_in; (void)out_size;

  hipMemsetAsync(cnt, 0, E_N * 4, stream);
  cvt_bf16_kernel<<<TT * DD / 4 / 256, 256, 0, stream>>>(x, Xb);
  router_kernel<<<TT, 256, 0, stream>>>(x, rw, cnt, list, tw);

  // --- gate/up weight transposes: [D][F(S)] -> [F(S)][D] bf16 ---
  tcvt_kernel<<<dim3(DD / 64, FF / 64, E_N), 256, 0, stream>>>(wg, W1, DD, FF);
  tcvt_kernel<<<dim3(DD / 64, FF / 64, E_N), 256, 0, stream>>>(wu, W2, DD, FF);
  tcvt_kernel<<<dim3(DD / 64, FSS / 64, 1), 256, 0, stream>>>(sg, W3, DD, FSS);
  tcvt_kernel<<<dim3(DD / 64, FSS / 64, 1), 256, 0, stream>>>(su, W4, DD, FSS);

  // --- ALL gate+up GEMMs, 8-phase 256x256 (z: 16 eG + 1 sG + 16 eU + 1 sU = 34) ---
  gu8_kernel<<<dim3(TT / 256, FSS / 256, 34), 512, 0, stream>>>(
      Xb, W1, W2, W3, W4, Gx, Hx, Gs, Hs, list, cnt);

  // --- h = silu(g)*u ---
  h_kernel<<<(size_t)4 * TT * FF / 8 / 256, 256, 0, stream>>>(Gx, Hx);
  h_kernel<<<(size_t)TT * FSS / 8 / 256, 256, 0, stream>>>(Gs, Hs);

  // --- down weight transposes (reuse W1/W2) ---
  tcvt_kernel<<<dim3(FF / 64, DD / 64, E_N), 256, 0, stream>>>(wd, W1, FF, DD);
  tcvt_kernel<<<dim3(FSS / 64, DD / 64, 1), 256, 0, stream>>>(sd, W2, FSS, DD);

  // --- both down GEMMs, 8-phase 256x256 (z: 16 expert + 1 shared) ---
  dn8_kernel<<<dim3(TT / 256, DD / 256, 17), 512, 0, stream>>>(
      Hx, Hs, W1, W2, Y, Ys, list, cnt, tw);

  combine_kernel<<<TT * DD / 4 / 256, 256, 0, stream>>>(Y, Ys, out);
}

// Round 10
// 1264.805 us; speedup vs baseline: 1.0146x; 1.0146x over previous
//
#include <hip/hip_runtime.h>
#include <hip/hip_bf16.h>
#include <stdint.h>

#define E_N 16
#define TOPK 4
#define DD 2560
#define FF 1664
#define FSS 3328
#define TT 2048

typedef __attribute__((ext_vector_type(8))) __bf16 bf16x8;
typedef __attribute__((ext_vector_type(4))) float f32x4;

__device__ __forceinline__ unsigned short f2bf(float f) {
  return __builtin_bit_cast(unsigned short, (__bf16)f);
}
__device__ __forceinline__ float bf2f(unsigned short u) {
  return __builtin_bit_cast(float, (unsigned int)u << 16);
}
__device__ __forceinline__ unsigned int pk2(float a, float b) {
  return (unsigned int)f2bf(a) | ((unsigned int)f2bf(b) << 16);
}

#define GLOAD16(g, l)                                                          \
  __builtin_amdgcn_global_load_lds(                                            \
      (const __attribute__((address_space(1))) void*)(g),                      \
      (__attribute__((address_space(3))) void*)(l), 16, 0, 0)

#define SBAR() __builtin_amdgcn_s_barrier()
#define VMW(N) asm volatile("s_waitcnt vmcnt(" #N ")" ::: "memory")

// swizzled block decompose: XCD-chunked bijective remap (requires nwg%8==0)
__device__ __forceinline__ void swz_block(int& bm, int& bn, int& bz) {
  int gx = gridDim.x, gy = gridDim.y;
  int nwg = gx * gy * gridDim.z;
  int flat = blockIdx.x + gx * (blockIdx.y + gy * blockIdx.z);
  if ((nwg & 7) == 0) flat = (flat & 7) * (nwg >> 3) + (flat >> 3);
  bm = flat % gx;
  int rest = flat / gx;
  bn = rest % gy;
  bz = rest / gy;
}

// ---------------- X -> bf16 ----------------
__global__ __launch_bounds__(256) void cvt_bf16_kernel(const float* __restrict__ in,
                                                       unsigned short* __restrict__ out) {
  size_t i = ((size_t)blockIdx.x * 256 + threadIdx.x) * 4;
  float4 v = *reinterpret_cast<const float4*>(in + i);
  ushort4 o;
  o.x = f2bf(v.x); o.y = f2bf(v.y); o.z = f2bf(v.z); o.w = f2bf(v.w);
  *reinterpret_cast<ushort4*>(out + i) = o;
}

// ---------------- weight transpose+convert: [K][N] f32 -> [N][K] bf16 ----------------
__global__ __launch_bounds__(256) void tcvt_kernel(const float* __restrict__ in,
                                                   unsigned short* __restrict__ out,
                                                   int K, int N) {
  __shared__ float lds[64 * 65];
  int z = blockIdx.z;
  in += (size_t)z * K * N;
  out += (size_t)z * K * N;
  int k0 = blockIdx.x * 64, n0 = blockIdx.y * 64;
  int t = threadIdx.x;
#pragma unroll
  for (int j = 0; j < 4; ++j) {
    int idx = j * 256 + t;
    int r = idx >> 4, c = (idx & 15) * 4;
    float4 v = *reinterpret_cast<const float4*>(in + (size_t)(k0 + r) * N + n0 + c);
    lds[r * 65 + c] = v.x;
    lds[r * 65 + c + 1] = v.y;
    lds[r * 65 + c + 2] = v.z;
    lds[r * 65 + c + 3] = v.w;
  }
  __syncthreads();
#pragma unroll
  for (int j = 0; j < 2; ++j) {
    int idx = j * 256 + t;
    int n = idx >> 3, kg = (idx & 7) * 8;
    float a0 = lds[(kg + 0) * 65 + n], a1 = lds[(kg + 1) * 65 + n];
    float a2 = lds[(kg + 2) * 65 + n], a3 = lds[(kg + 3) * 65 + n];
    float a4 = lds[(kg + 4) * 65 + n], a5 = lds[(kg + 5) * 65 + n];
    float a6 = lds[(kg + 6) * 65 + n], a7 = lds[(kg + 7) * 65 + n];
    uint4 o{pk2(a0, a1), pk2(a2, a3), pk2(a4, a5), pk2(a6, a7)};
    *reinterpret_cast<uint4*>(out + (size_t)(n0 + n) * K + k0 + kg) = o;
  }
}

// ---------------- Router ----------------
__global__ __launch_bounds__(256) void router_kernel(const float* __restrict__ x,
                                                     const float* __restrict__ rw,
                                                     int* __restrict__ cnt,
                                                     int* __restrict__ list,
                                                     float* __restrict__ tw) {
  int t = blockIdx.x;
  const float* xr = x + (size_t)t * DD;
  __shared__ float logits[E_N];
  int lane = threadIdx.x & 63, wid = threadIdx.x >> 6;
  for (int ee = 0; ee < 4; ++ee) {
    int e = wid * 4 + ee;
    const float* wr = rw + (size_t)e * DD;
    float p = 0.f;
    for (int d = lane; d < DD; d += 64) p += xr[d] * wr[d];
#pragma unroll
    for (int off = 32; off > 0; off >>= 1) p += __shfl_down(p, off);
    if (lane == 0) logits[e] = p;
  }
  __syncthreads();
  if (threadIdx.x == 0) {
    float mx = -1e30f;
    for (int e = 0; e < E_N; ++e) mx = fmaxf(mx, logits[e]);
    float pe[E_N];
    for (int e = 0; e < E_N; ++e) pe[e] = __expf(logits[e] - mx);
    int idx[TOPK]; float val[TOPK]; float s4 = 0.f;
    unsigned used = 0;
    for (int k = 0; k < TOPK; ++k) {
      int bi = 0; float bv = -1.f;
      for (int e = 0; e < E_N; ++e)
        if (!((used >> e) & 1) && pe[e] > bv) { bv = pe[e]; bi = e; }
      used |= 1u << bi; idx[k] = bi; val[k] = bv; s4 += bv;
    }
    float inv = 1.f / s4;
    for (int k = 0; k < TOPK; ++k) {
      int e2 = idx[k];
      int pos = atomicAdd(&cnt[e2], 1);
      list[e2 * TT + pos] = t * 4 + k;
      tw[t * 4 + k] = val[k] * inv;
    }
  }
}

// ---------------- 256x256 half-tile double-buffered GEMM body ----------------
// BM=BN=256, BK=64 (2 halves of 32), 512 threads / 8 waves (2M x 4N).
// LDS: 2 bufs x [A half0|A half1|B half0|B half1] x 256x32 bf16 = 128KB.
// Counted vmcnt(8) per half; ONE barrier per half; stage issued post-barrier;
// no sched_barrier pinning — compiler interleaves loads/ds_reads/MFMA.
template <int MODE, int SHIFT>
__device__ __forceinline__ void gemm256(
    const unsigned short* __restrict__ A0, const unsigned short* __restrict__ W0,
    void* __restrict__ O0, const int* lst, const float* __restrict__ tw,
    int M, int Kt, int Nt, int m0, int n0) {
  __shared__ __align__(16) unsigned short lds[2][32768];

  int tid = threadIdx.x, lane = tid & 63, w = tid >> 6;
  int wm = w >> 2, wn = w & 3;

  // staging pointers: chunk id = j*512+tid -> row id>>2, chunk id&3 (source-swizzled)
  const unsigned short* pA[2];
  const unsigned short* pB[2];
#pragma unroll
  for (int j = 0; j < 2; ++j) {
    int id = j * 512 + tid;
    int row = id >> 2, c = id & 3;
    int cs = c ^ ((row >> 1) & 3);   // 64B-row involution
    int ar = min(m0 + row, M - 1);
    int code = lst ? lst[ar] : ar;
    int arow = SHIFT ? (lst ? (code >> 2) : code) : code;
    pA[j] = A0 + (size_t)arow * Kt + cs * 8;
    int br = min(n0 + row, Nt - 1);
    pB[j] = W0 + (size_t)br * Kt + cs * 8;
  }

  // stage half h of tile kt into buf (4 gloads/thread = 8/thread/tile)
  auto stage = [&](int kt, int h, int buf) {
    int koff = kt * 64 + h * 32;
    unsigned short* dA = &lds[buf][h * 8192];
    unsigned short* dB = &lds[buf][16384 + h * 8192];
#pragma unroll
    for (int j = 0; j < 2; ++j) {
      GLOAD16(pA[j] + koff, dA + (j * 512 + tid) * 8);
      GLOAD16(pB[j] + koff, dB + (j * 512 + tid) * 8);
    }
  };

  int cg = lane >> 4;
  int aoff[8], boff[4];
#pragma unroll
  for (int mf = 0; mf < 8; ++mf) {
    int r = wm * 128 + mf * 16 + (lane & 15);
    aoff[mf] = r * 32 + ((cg ^ ((r >> 1) & 3)) * 8);
  }
#pragma unroll
  for (int nf = 0; nf < 4; ++nf) {
    int rb = wn * 64 + nf * 16 + (lane & 15);
    boff[nf] = 16384 + rb * 32 + ((cg ^ ((rb >> 1) & 3)) * 8);
  }

  f32x4 acc[8][4] = {};

  // compute one 32-K half: base shift h*8192 applies to both A and B sections
  auto half_compute = [&](int buf, int h) {
    const unsigned short* L = &lds[buf][h * 8192];
    bf16x8 a[8], b[4];
#pragma unroll
    for (int nf = 0; nf < 4; ++nf)
      b[nf] = __builtin_bit_cast(bf16x8, *reinterpret_cast<const uint4*>(L + boff[nf]));
#pragma unroll
    for (int mf = 0; mf < 8; ++mf)
      a[mf] = __builtin_bit_cast(bf16x8, *reinterpret_cast<const uint4*>(L + aoff[mf]));
    __builtin_amdgcn_s_setprio(1);
#pragma unroll
    for (int mf = 0; mf < 8; ++mf)
#pragma unroll
      for (int nf = 0; nf < 4; ++nf)
        acc[mf][nf] = __builtin_amdgcn_mfma_f32_16x16x32_bf16(a[mf], b[nf], acc[mf][nf], 0, 0, 0);
    __builtin_amdgcn_s_setprio(0);
  };

  int nk = Kt / 64;
  stage(0, 0, 0);
  stage(0, 1, 0);
  stage(1, 0, 1);                    // 12 gloads outstanding
  for (int kt = 0; kt < nk; ++kt) {
    int buf = kt & 1;
    // ---- half 0 ----
    if (kt + 1 < nk) { VMW(8); } else { VMW(4); }   // (kt,0) landed
    SBAR();
    if (kt + 1 < nk) stage(kt + 1, 1, buf ^ 1);
    half_compute(buf, 0);
    // ---- half 1 ----
    if (kt + 1 < nk) { VMW(8); } else { VMW(0); }   // (kt,1) landed
    SBAR();
    if (kt + 2 < nk) stage(kt + 2, 0, buf);         // overwrites buf half0 (read done)
    half_compute(buf, 1);
  }

  // epilogue (C/D: col=lane&15, row=(lane>>4)*4+q per 16x16 frag)
#pragma unroll
  for (int mf = 0; mf < 8; ++mf) {
#pragma unroll
    for (int q = 0; q < 4; ++q) {
      int lr = wm * 128 + mf * 16 + (lane >> 4) * 4 + q;
      int grow = m0 + lr;
      if (grow < M) {
        int code = lst ? lst[grow] : grow;
        int col = n0 + wn * 64 + (lane & 15);
        if (MODE == 0) {
          unsigned short* Op = (unsigned short*)O0 + (size_t)code * Nt + col;
#pragma unroll
          for (int nf = 0; nf < 4; ++nf)
            if (col + nf * 16 < Nt) Op[nf * 16] = f2bf(acc[mf][nf][q]);
        } else {
          float scale = tw ? tw[code] : 1.f;
          float* Op = (float*)O0 + (size_t)code * Nt + col;
#pragma unroll
          for (int nf = 0; nf < 4; ++nf)
            if (col + nf * 16 < Nt) Op[nf * 16] = acc[mf][nf][q] * scale;
        }
      }
    }
  }
}

// ---------------- mega gate+up launch: z=0..15 expert-G, 16 shared-G,
//                  17..32 expert-U, 33 shared-U ----------------
__global__ __launch_bounds__(512, 1) void gu256_kernel(
    const unsigned short* __restrict__ Xb,
    const unsigned short* __restrict__ WgT, const unsigned short* __restrict__ WuT,
    const unsigned short* __restrict__ SgT, const unsigned short* __restrict__ SuT,
    unsigned short* __restrict__ Gx, unsigned short* __restrict__ Ux,
    unsigned short* __restrict__ Gs, unsigned short* __restrict__ Us,
    const int* __restrict__ list, const int* __restrict__ cnt) {
  int bm, bn, z;
  swz_block(bm, bn, z);
  bool up = z >= 17;
  int ze = up ? z - 17 : z;
  const unsigned short* W0;
  unsigned short* O0;
  const int* lst = nullptr;
  int M, Nt;
  if (ze < E_N) {
    M = cnt[ze];
    lst = list + ze * TT;
    Nt = FF;
    W0 = (up ? WuT : WgT) + (size_t)ze * DD * FF;
    O0 = up ? Ux : Gx;
  } else {
    M = TT;
    Nt = FSS;
    W0 = up ? SuT : SgT;
    O0 = up ? Us : Gs;
  }
  int m0 = bm * 256, n0 = bn * 256;
  if (m0 >= M || n0 >= Nt) return;
  gemm256<0, 1>(Xb, W0, O0, lst, nullptr, M, DD, Nt, m0, n0);
}

// ---------------- mega down launch: z=0..15 expert, 16 shared ----------------
__global__ __launch_bounds__(512, 1) void dn256_kernel(
    const unsigned short* __restrict__ Hx, const unsigned short* __restrict__ Hs,
    const unsigned short* __restrict__ WdT, const unsigned short* __restrict__ SdT,
    float* __restrict__ Y, float* __restrict__ Ys,
    const int* __restrict__ list, const int* __restrict__ cnt,
    const float* __restrict__ tw) {
  int bm, bn, z;
  swz_block(bm, bn, z);
  const unsigned short* A0;
  const unsigned short* W0;
  float* O0;
  const int* lst = nullptr;
  const float* sc = nullptr;
  int M, Kt;
  if (z < E_N) {
    M = cnt[z];
    lst = list + z * TT;
    Kt = FF;
    A0 = Hx;
    W0 = WdT + (size_t)z * FF * DD;
    O0 = Y;
    sc = tw;
  } else {
    M = TT;
    Kt = FSS;
    A0 = Hs;
    W0 = SdT;
    O0 = Ys;
  }
  int m0 = bm * 256, n0 = bn * 256;
  if (m0 >= M) return;
  gemm256<1, 0>(A0, W0, O0, lst, sc, M, Kt, DD, m0, n0);
}

// ---------------- h = silu(g) * u, elementwise in-place on u ----------------
__global__ __launch_bounds__(256) void h_kernel(const unsigned short* __restrict__ g,
                                                unsigned short* __restrict__ u) {
  size_t i = ((size_t)blockIdx.x * 256 + threadIdx.x) * 8;
  uint4 gv = *reinterpret_cast<const uint4*>(g + i);
  uint4 uv = *reinterpret_cast<const uint4*>(u + i);
  const unsigned int* gw = reinterpret_cast<const unsigned int*>(&gv);
  const unsigned int* uw = reinterpret_cast<const unsigned int*>(&uv);
  uint4 ov;
  unsigned int* ow = reinterpret_cast<unsigned int*>(&ov);
#pragma unroll
  for (int j = 0; j < 4; ++j) {
    float g0 = bf2f((unsigned short)(gw[j] & 0xffff));
    float g1 = bf2f((unsigned short)(gw[j] >> 16));
    float u0 = bf2f((unsigned short)(uw[j] & 0xffff));
    float u1 = bf2f((unsigned short)(uw[j] >> 16));
    float h0 = (g0 / (1.f + __expf(-g0))) * u0;
    float h1 = (g1 / (1.f + __expf(-g1))) * u1;
    ow[j] = pk2(h0, h1);
  }
  *reinterpret_cast<uint4*>(u + i) = ov;
}

// ---------------- combine ----------------
__global__ __launch_bounds__(256) void combine_kernel(const float* __restrict__ Y,
                                                      const float* __restrict__ Ys,
                                                      float* __restrict__ out) {
  size_t i = ((size_t)blockIdx.x * 256 + threadIdx.x) * 4;
  size_t t = i / DD;
  int d = (int)(i % DD);
  float4 a = *reinterpret_cast<const float4*>(Ys + i);
#pragma unroll
  for (int k = 0; k < 4; ++k) {
    float4 v = *reinterpret_cast<const float4*>(Y + (t * 4 + k) * (size_t)DD + d);
    a.x += v.x; a.y += v.y; a.z += v.z; a.w += v.w;
  }
  *reinterpret_cast<float4*>(out + i) = a;
}

extern "C" void kernel_launch(void* const* d_in, const int* in_sizes, int n_in,
                              void* d_out, int out_size, void* d_ws, size_t ws_size,
                              hipStream_t stream) {
  const float* x  = (const float*)d_in[0];
  const float* rw = (const float*)d_in[1];
  const float* wg = (const float*)d_in[2];
  const float* wu = (const float*)d_in[3];
  const float* wd = (const float*)d_in[4];
  const float* sg = (const float*)d_in[5];
  const float* su = (const float*)d_in[6];
  const float* sd = (const float*)d_in[7];
  float* out = (float*)d_out;

  char* ws = (char*)d_ws;
  size_t off = 0;
  auto alloc = [&](size_t bytes) {
    off = (off + 255) & ~(size_t)255;
    void* p = ws + off;
    off += bytes;
    return p;
  };
  unsigned short* W1 = (unsigned short*)alloc((size_t)E_N * FF * DD * 2);   // 136 MB
  unsigned short* W2 = (unsigned short*)alloc((size_t)E_N * FF * DD * 2);   // 136 MB
  unsigned short* W3 = (unsigned short*)alloc((size_t)FSS * DD * 2);        // 17 MB
  unsigned short* W4 = (unsigned short*)alloc((size_t)FSS * DD * 2);        // 17 MB
  unsigned short* Xb = (unsigned short*)alloc((size_t)TT * DD * 2);
  unsigned short* Gx = (unsigned short*)alloc((size_t)4 * TT * FF * 2);     // raw expert G
  unsigned short* Hx = (unsigned short*)alloc((size_t)4 * TT * FF * 2);     // raw U -> H
  unsigned short* Gs = (unsigned short*)alloc((size_t)TT * FSS * 2);
  unsigned short* Hs = (unsigned short*)alloc((size_t)TT * FSS * 2);
  float* Y  = (float*)alloc((size_t)4 * TT * DD * 4);
  float* Ys = (float*)alloc((size_t)TT * DD * 4);
  float* tw = (float*)alloc((size_t)4 * TT * 4);
  int* cnt  = (int*)alloc(E_N * 4);
  int* list = (int*)alloc((size_t)E_N * TT * 4);
  (void)ws_size; (void)in_sizes; (void)n_in; (void)out_size;

  hipMemsetAsync(cnt, 0, E_N * 4, stream);
  cvt_bf16_kernel<<<TT * DD / 4 / 256, 256, 0, stream>>>(x, Xb);
  router_kernel<<<TT, 256, 0, stream>>>(x, rw, cnt, list, tw);

  // --- gate/up weight transposes: [D][F(S)] -> [F(S)][D] bf16 ---
  tcvt_kernel<<<dim3(DD / 64, FF / 64, E_N), 256, 0, stream>>>(wg, W1, DD, FF);
  tcvt_kernel<<<dim3(DD / 64, FF / 64, E_N), 256, 0, stream>>>(wu, W2, DD, FF);
  tcvt_kernel<<<dim3(DD / 64, FSS / 64, 1), 256, 0, stream>>>(sg, W3, DD, FSS);
  tcvt_kernel<<<dim3(DD / 64, FSS / 64, 1), 256, 0, stream>>>(su, W4, DD, FSS);

  // --- ALL gate+up GEMMs, 256x256 half-pipelined (z: 16 eG + 1 sG + 16 eU + 1 sU) ---
  gu256_kernel<<<dim3(TT / 256, (FSS + 255) / 256, 34), 512, 0, stream>>>(
      Xb, W1, W2, W3, W4, Gx, Hx, Gs, Hs, list, cnt);

  // --- h = silu(g)*u ---
  h_kernel<<<(size_t)4 * TT * FF / 8 / 256, 256, 0, stream>>>(Gx, Hx);
  h_kernel<<<(size_t)TT * FSS / 8 / 256, 256, 0, stream>>>(Gs, Hs);

  // --- down weight transposes (reuse W1/W2) ---
  tcvt_kernel<<<dim3(FF / 64, DD / 64, E_N), 256, 0, stream>>>(wd, W1, FF, DD);
  tcvt_kernel<<<dim3(FSS / 64, DD / 64, 1), 256, 0, stream>>>(sd, W2, FSS, DD);

  // --- both down GEMMs, 256x256 (z: 16 expert + 1 shared) ---
  dn256_kernel<<<dim3(TT / 256, DD / 256, 17), 512, 0, stream>>>(
      Hx, Hs, W1, W2, Y, Ys, list, cnt, tw);

  combine_kernel<<<TT * DD / 4 / 256, 256, 0, stream>>>(Y, Ys, out);
}